// Round 1
// baseline (1374.365 us; speedup 1.0000x reference)
//
#include <hip/hip_runtime.h>
#include <hip/hip_bf16.h>
#include <math.h>

#define NNODE 50000
#define NEDGE 800000
#define DD 128

typedef __bf16 bf16x8 __attribute__((ext_vector_type(8)));
typedef __bf16 bf16x4 __attribute__((ext_vector_type(4)));
typedef float f32x4 __attribute__((ext_vector_type(4)));

#define MFMA_BF16 __builtin_amdgcn_mfma_f32_16x16x32_bf16

// ---- packed weight layout (bf16 elements, MFMA B-fragment order) ----
// frag(kc,nt): 512 elems, elem index = lane*8 + j, maps to W[kc*32 + (lane>>4)*8 + j][nt*16 + (lane&15)]
// ew1: base 0      (96 frags, K=384)
// ew2: base 49152  (32 frags, K=128)
// ew3: base 65536  (32 frags, K=128)
// nw1: base 81920  (64 frags, K=256)
// nw2: base 114688 (32 frags, K=128)
// nw3: base 131072 (32 frags, K=128)
#define WPK_TOTAL 147456

__global__ void pack_weights(const float* ew1, const float* ew2, const float* ew3,
                             const float* nw1, const float* nw2, const float* nw3,
                             __bf16* out) {
    int t = blockIdx.x * 256 + threadIdx.x;
    if (t >= WPK_TOTAL) return;
    const float* W; int base;
    if (t < 49152)       { W = ew1; base = 0; }
    else if (t < 65536)  { W = ew2; base = 49152; }
    else if (t < 81920)  { W = ew3; base = 65536; }
    else if (t < 114688) { W = nw1; base = 81920; }
    else if (t < 131072) { W = nw2; base = 114688; }
    else                 { W = nw3; base = 131072; }
    int local = t - base;
    int frag = local >> 9;
    int rem  = local & 511;
    int lane = rem >> 3;
    int j    = rem & 7;
    int kc = frag >> 3, nt = frag & 7;
    int k = kc * 32 + (lane >> 4) * 8 + j;
    int n = nt * 16 + (lane & 15);
    out[t] = (__bf16)W[k * 128 + n];
}

// generic MFMA stage: wave computes 64 rows x 32 cols (nt = 2w, 2w+1), K = KC*32
template <int KC, int STRIDE>
__device__ inline void mm_stage(const __bf16* ldsA, int colbase,
                                const __bf16* wpk, int woff,
                                int l, int l15, int quad, int w,
                                f32x4 acc[4][2]) {
    for (int kc = 0; kc < KC; ++kc) {
        bf16x8 a[4];
#pragma unroll
        for (int rt = 0; rt < 4; ++rt)
            a[rt] = *(const bf16x8*)&ldsA[(rt * 16 + l15) * STRIDE + colbase + kc * 32 + quad * 8];
        bf16x8 b[2];
#pragma unroll
        for (int nh = 0; nh < 2; ++nh) {
            int nt = 2 * w + nh;
            b[nh] = *(const bf16x8*)&wpk[woff + (kc * 8 + nt) * 512 + l * 8];
        }
#pragma unroll
        for (int rt = 0; rt < 4; ++rt)
#pragma unroll
            for (int nh = 0; nh < 2; ++nh)
                acc[rt][nh] = MFMA_BF16(a[rt], b[nh], acc[rt][nh], 0, 0, 0);
    }
}

// bias + silu + store bf16 into LDS (C-layout: row = rt*16 + quad*4 + reg, col = nt*16 + l15)
template <int STRIDE>
__device__ inline void silu_store(const f32x4 acc[4][2], float bc0, float bc1,
                                  __bf16* ldsH, int colbase,
                                  int l15, int quad, int w) {
#pragma unroll
    for (int rt = 0; rt < 4; ++rt)
#pragma unroll
        for (int nh = 0; nh < 2; ++nh) {
            int col = (2 * w + nh) * 16 + l15;
            float bc = nh ? bc1 : bc0;
#pragma unroll
            for (int reg = 0; reg < 4; ++reg) {
                float v = acc[rt][nh][reg] + bc;
                v = v / (1.0f + __expf(-v));
                int row = rt * 16 + quad * 4 + reg;
                ldsH[row * STRIDE + colbase + col] = (__bf16)v;
            }
        }
}

// ---------------- edge kernel: 64 edges per block, 256 threads ----------------
__global__ __launch_bounds__(256, 3) void edge_kernel(
    const float* __restrict__ x, const int* __restrict__ ei, const float* __restrict__ ea,
    const __bf16* __restrict__ wpk,
    const float* __restrict__ eb1, const float* __restrict__ eb2, const float* __restrict__ eb3,
    const float* __restrict__ lng, const float* __restrict__ lnb,
    float* __restrict__ out) {
    __shared__ __bf16 lds_e[64 * 392];   // e_in tile, 384 cols + 8 pad; h1 aliases cols 0..127, h2 cols 128..255
    __shared__ float lds_part[64][8];    // LN partials [row][wave*2 + {sum,sumsq}]
    __shared__ int lds_i[64], lds_j[64];

    const int tid = threadIdx.x;
    const int l = tid & 63, w = tid >> 6;
    const int l15 = l & 15, quad = l >> 4;
    const int e0 = blockIdx.x * 64;

    // per-lane column constants
    const int col0 = (2 * w) * 16 + l15, col1 = col0 + 16;
    const float b1c0 = eb1[col0], b1c1 = eb1[col1];
    const float b2c0 = eb2[col0], b2c1 = eb2[col1];
    const float b3c0 = eb3[col0], b3c1 = eb3[col1];
    const float g0 = lng[col0], g1 = lng[col1];
    const float lb0 = lnb[col0], lb1 = lnb[col1];

    if (tid < 64) lds_i[tid] = ei[e0 + tid];
    else if (tid < 128) lds_j[tid - 64] = ei[NEDGE + e0 + (tid - 64)];
    __syncthreads();

    // stage e_in = [x[i] | x[j] | ea] as bf16
    for (int t = tid; t < 64 * 96; t += 256) {
        int row = t / 96;
        int q = t - row * 96;
        int seg = q >> 5, c = q & 31;
        const float* src;
        if (seg == 0)      src = x + (size_t)lds_i[row] * 128 + c * 4;
        else if (seg == 1) src = x + (size_t)lds_j[row] * 128 + c * 4;
        else               src = ea + (size_t)(e0 + row) * 128 + c * 4;
        float4 v = *(const float4*)src;
        bf16x4 bv = { (__bf16)v.x, (__bf16)v.y, (__bf16)v.z, (__bf16)v.w };
        *(bf16x4*)&lds_e[row * 392 + seg * 128 + c * 4] = bv;
    }
    __syncthreads();

    // stage 1: [64,384] @ ew1 -> h1
    f32x4 acc[4][2] = {};
    mm_stage<12, 392>(lds_e, 0, wpk, 0, l, l15, quad, w, acc);
    __syncthreads();                                   // everyone done reading e_in cols 0..127
    silu_store<392>(acc, b1c0, b1c1, lds_e, 0, l15, quad, w);   // h1 -> cols 0..127
    __syncthreads();

    // stage 2: h1 @ ew2 -> h2
    f32x4 acc2[4][2] = {};
    mm_stage<4, 392>(lds_e, 0, wpk, 49152, l, l15, quad, w, acc2);
    silu_store<392>(acc2, b2c0, b2c1, lds_e, 128, l15, quad, w); // h2 -> cols 128..255 (not read by stage 2)
    __syncthreads();

    // stage 3: h2 @ ew3 -> e3
    f32x4 acc3[4][2] = {};
    mm_stage<4, 392>(lds_e, 128, wpk, 65536, l, l15, quad, w, acc3);

    // LayerNorm partials (per row: sum, sumsq over this wave's 32 cols)
#pragma unroll
    for (int rt = 0; rt < 4; ++rt)
#pragma unroll
        for (int reg = 0; reg < 4; ++reg) {
            float v0 = acc3[rt][0][reg] + b3c0;
            float v1 = acc3[rt][1][reg] + b3c1;
            float s = v0 + v1, q = v0 * v0 + v1 * v1;
#pragma unroll
            for (int off = 1; off < 16; off <<= 1) {
                s += __shfl_xor(s, off);
                q += __shfl_xor(q, off);
            }
            if (l15 == 0) {
                int row = rt * 16 + quad * 4 + reg;
                lds_part[row][2 * w] = s;
                lds_part[row][2 * w + 1] = q;
            }
        }
    __syncthreads();

    // finalize: LN, residual, store edge_attr_new, scatter-add into agg (= out[0 : N*128])
#pragma unroll
    for (int rt = 0; rt < 4; ++rt)
#pragma unroll
        for (int reg = 0; reg < 4; ++reg) {
            int row = rt * 16 + quad * 4 + reg;
            float4 p0 = *(const float4*)&lds_part[row][0];
            float4 p1 = *(const float4*)&lds_part[row][4];
            float stot = p0.x + p0.z + p1.x + p1.z;
            float qtot = p0.y + p0.w + p1.y + p1.w;
            float mean = stot * (1.0f / 128.0f);
            float var = qtot * (1.0f / 128.0f) - mean * mean;
            float rstd = rsqrtf(var + 1e-5f);
            int e = e0 + row;
            int jn = lds_j[row];
#pragma unroll
            for (int nh = 0; nh < 2; ++nh) {
                int col = (2 * w + nh) * 16 + l15;
                float v = acc3[rt][nh][reg] + (nh ? b3c1 : b3c0);
                float o = (v - mean) * rstd * (nh ? g1 : g0) + (nh ? lb1 : lb0);
                float res = o + (float)lds_e[row * 392 + 256 + col];
                out[(size_t)NNODE * 128 + (size_t)e * 128 + col] = res;
                atomicAdd(&out[(size_t)jn * 128 + col], res);
            }
        }
}

// ---------------- node kernel: 64 nodes per block ----------------
__global__ __launch_bounds__(256, 3) void node_kernel(
    const float* __restrict__ x, const __bf16* __restrict__ wpk,
    const float* __restrict__ nb1, const float* __restrict__ nb2, const float* __restrict__ nb3,
    const float* __restrict__ lng, const float* __restrict__ lnb,
    float* __restrict__ out) {
    __shared__ __bf16 lds_n[64 * 264];   // [x | agg] 256 cols + 8 pad; h1 aliases cols 0..127, h2 cols 128..255
    __shared__ float lds_part[64][8];

    const int tid = threadIdx.x;
    const int l = tid & 63, w = tid >> 6;
    const int l15 = l & 15, quad = l >> 4;
    const int r0 = blockIdx.x * 64;

    const int col0 = (2 * w) * 16 + l15, col1 = col0 + 16;
    const float b1c0 = nb1[col0], b1c1 = nb1[col1];
    const float b2c0 = nb2[col0], b2c1 = nb2[col1];
    const float b3c0 = nb3[col0], b3c1 = nb3[col1];
    const float g0 = lng[col0], g1 = lng[col1];
    const float lb0 = lnb[col0], lb1 = lnb[col1];

    // stage n_in = [x | agg] (agg lives in out[0 : N*128], produced by edge kernel atomics)
    for (int t = tid; t < 64 * 64; t += 256) {
        int row = t >> 6;
        int q = t & 63;
        int seg = q >> 5, c = q & 31;
        int r = r0 + row;
        float4 v = make_float4(0.f, 0.f, 0.f, 0.f);
        if (r < NNODE) {
            const float* src = (seg == 0) ? (x + (size_t)r * 128 + c * 4)
                                          : (out + (size_t)r * 128 + c * 4);
            v = *(const float4*)src;
        }
        bf16x4 bv = { (__bf16)v.x, (__bf16)v.y, (__bf16)v.z, (__bf16)v.w };
        *(bf16x4*)&lds_n[row * 264 + seg * 128 + c * 4] = bv;
    }
    __syncthreads();

    // stage 1: [64,256] @ nw1 -> h1
    f32x4 acc[4][2] = {};
    mm_stage<8, 264>(lds_n, 0, wpk, 81920, l, l15, quad, w, acc);
    __syncthreads();
    silu_store<264>(acc, b1c0, b1c1, lds_n, 0, l15, quad, w);
    __syncthreads();

    // stage 2: h1 @ nw2 -> h2
    f32x4 acc2[4][2] = {};
    mm_stage<4, 264>(lds_n, 0, wpk, 114688, l, l15, quad, w, acc2);
    silu_store<264>(acc2, b2c0, b2c1, lds_n, 128, l15, quad, w);
    __syncthreads();

    // stage 3: h2 @ nw3 -> n3
    f32x4 acc3[4][2] = {};
    mm_stage<4, 264>(lds_n, 128, wpk, 131072, l, l15, quad, w, acc3);

#pragma unroll
    for (int rt = 0; rt < 4; ++rt)
#pragma unroll
        for (int reg = 0; reg < 4; ++reg) {
            float v0 = acc3[rt][0][reg] + b3c0;
            float v1 = acc3[rt][1][reg] + b3c1;
            float s = v0 + v1, q = v0 * v0 + v1 * v1;
#pragma unroll
            for (int off = 1; off < 16; off <<= 1) {
                s += __shfl_xor(s, off);
                q += __shfl_xor(q, off);
            }
            if (l15 == 0) {
                int row = rt * 16 + quad * 4 + reg;
                lds_part[row][2 * w] = s;
                lds_part[row][2 * w + 1] = q;
            }
        }
    __syncthreads();

#pragma unroll
    for (int rt = 0; rt < 4; ++rt)
#pragma unroll
        for (int reg = 0; reg < 4; ++reg) {
            int row = rt * 16 + quad * 4 + reg;
            int r = r0 + row;
            if (r >= NNODE) continue;
            float4 p0 = *(const float4*)&lds_part[row][0];
            float4 p1 = *(const float4*)&lds_part[row][4];
            float stot = p0.x + p0.z + p1.x + p1.z;
            float qtot = p0.y + p0.w + p1.y + p1.w;
            float mean = stot * (1.0f / 128.0f);
            float var = qtot * (1.0f / 128.0f) - mean * mean;
            float rstd = rsqrtf(var + 1e-5f);
#pragma unroll
            for (int nh = 0; nh < 2; ++nh) {
                int col = (2 * w + nh) * 16 + l15;
                float v = acc3[rt][nh][reg] + (nh ? b3c1 : b3c0);
                float o = (v - mean) * rstd * (nh ? g1 : g0) + (nh ? lb1 : lb0);
                float res = o + x[(size_t)r * 128 + col];   // residual: x_new = x + n_out
                out[(size_t)r * 128 + col] = res;           // overwrites agg (own row, after staging)
            }
        }
}

extern "C" void kernel_launch(void* const* d_in, const int* in_sizes, int n_in,
                              void* d_out, int out_size, void* d_ws, size_t ws_size,
                              hipStream_t stream) {
    const float* x    = (const float*)d_in[0];
    const int*   ei   = (const int*)  d_in[1];
    const float* ea   = (const float*)d_in[2];
    const float* ew1  = (const float*)d_in[3];
    const float* eb1  = (const float*)d_in[4];
    const float* ew2  = (const float*)d_in[5];
    const float* eb2  = (const float*)d_in[6];
    const float* ew3  = (const float*)d_in[7];
    const float* eb3  = (const float*)d_in[8];
    const float* elng = (const float*)d_in[9];
    const float* elnb = (const float*)d_in[10];
    const float* nw1  = (const float*)d_in[11];
    const float* nb1  = (const float*)d_in[12];
    const float* nw2  = (const float*)d_in[13];
    const float* nb2  = (const float*)d_in[14];
    const float* nw3  = (const float*)d_in[15];
    const float* nb3  = (const float*)d_in[16];
    const float* nlng = (const float*)d_in[17];
    const float* nlnb = (const float*)d_in[18];
    float* out = (float*)d_out;
    __bf16* wpk = (__bf16*)d_ws;

    // zero the x_new region: it doubles as the agg accumulator for the edge-kernel scatter
    hipMemsetAsync(out, 0, (size_t)NNODE * 128 * sizeof(float), stream);
    pack_weights<<<(WPK_TOTAL + 255) / 256, 256, 0, stream>>>(ew1, ew2, ew3, nw1, nw2, nw3, wpk);
    edge_kernel<<<NEDGE / 64, 256, 0, stream>>>(x, ei, ea, wpk, eb1, eb2, eb3, elng, elnb, out);
    node_kernel<<<(NNODE + 63) / 64, 256, 0, stream>>>(x, wpk, nb1, nb2, nb3, nlng, nlnb, out);
}